// Round 5
// baseline (241.481 us; speedup 1.0000x reference)
//
#include <hip/hip_runtime.h>
#include <hip/hip_bf16.h>
#include <stdint.h>

#define DIMN 1024
#define HEADS 16
#define HD 64
#define BATCH 4
#define SEQ 4096
#define M_TOT (BATCH*SEQ)   // 16384

typedef __attribute__((ext_vector_type(8))) __bf16 bf16x8;
typedef __attribute__((ext_vector_type(4))) __bf16 bf16x4;
typedef __attribute__((ext_vector_type(4))) float f32x4;

__device__ __forceinline__ void gload_lds16(const void* g, void* l) {
  __builtin_amdgcn_global_load_lds(
      (const __attribute__((address_space(1))) void*)(uintptr_t)g,
      (__attribute__((address_space(3))) void*)(uint32_t)(uintptr_t)l,
      16, 0, 0);
}

__device__ __forceinline__ uint32_t swz128(uint32_t off) {
  return off ^ (((off >> 7) & 7) << 4);
}

__device__ __forceinline__ void lfence() { asm volatile("" ::: "memory"); }
__device__ __forceinline__ void barx() { lfence(); __builtin_amdgcn_s_barrier(); lfence(); }

// ---------------- fused cast: x (4194304 quads) then Wq/Wk/Wv/Wp (262144 each) ----------------
__global__ __launch_bounds__(256) void cast_all_kernel(const float* __restrict__ x,
                                                       const float* __restrict__ wq,
                                                       const float* __restrict__ wk,
                                                       const float* __restrict__ wv,
                                                       const float* __restrict__ wp,
                                                       __bf16* __restrict__ xb,
                                                       __bf16* __restrict__ wqb,
                                                       __bf16* __restrict__ wkb,
                                                       __bf16* __restrict__ wvb,
                                                       __bf16* __restrict__ wpb) {
  int i = blockIdx.x * 256 + threadIdx.x;
  const float* src; __bf16* dst; int j;
  if (i < 4194304)      { src = x;  dst = xb;  j = i; }
  else {
    int t = i - 4194304;
    int w = t >> 18; j = t & 262143;
    if      (w == 0) { src = wq; dst = wqb; }
    else if (w == 1) { src = wk; dst = wkb; }
    else if (w == 2) { src = wv; dst = wvb; }
    else             { src = wp; dst = wpb; }
  }
  f32x4 v = ((const f32x4*)src)[j];
  bf16x4 o;
  o[0] = (__bf16)v[0]; o[1] = (__bf16)v[1]; o[2] = (__bf16)v[2]; o[3] = (__bf16)v[3];
  ((bf16x4*)dst)[j] = o;
}

// ---------------- 256x256 8-phase GEMM: C = A[M,1024] @ W[N,1024]^T ----------------
// Operand-swapped MFMA (mfma(B,A)) -> D^T fragments: lane holds 4 consecutive
// OUTPUT COLUMNS of one row -> vectorized 8B/16B epilogue stores.
// MODE 2: v + bias -> f32 row-major [M,1024]
// MODE 3: fused QKV: n<1024 -> q (elu+1), <2048 -> k (elu+1), else v; bf16 head layout
template <int MODE, int NT>
__global__ __launch_bounds__(512, 2) void gemm256(const __bf16* __restrict__ A,
                                                  const __bf16* __restrict__ Bw,
                                                  void* __restrict__ Cout,
                                                  const float* __restrict__ bias) {
  __shared__ char lds[131072];   // A: [0,65536) bufs 0/1; B: [65536,131072)
  const int KB = DIMN * 2;       // 2048 B row stride
  const int NKT = DIMN / 64;     // 16 K-tiles
  const int bid = blockIdx.x;
  const int x = bid & 7, jj = bid >> 3;
  const int n_t = jj % NT, m_t = (jj / NT) * 8 + x;
  const int m0 = m_t * 256, n0 = n_t * 256;
  const int tid = threadIdx.x;
  const int lane = tid & 63;
  const int wave = tid >> 6;
  const int wm = wave >> 2;        // 0..1
  const int wn = wave & 3;         // 0..3
  const int r16 = lane & 15, r4 = lane >> 4;

  const uint32_t s_off0 = tid * 16;
  const uint32_t s_off1 = 8192 + tid * 16;
  const uint32_t s_row0 = s_off0 >> 7, s_row1 = s_off1 >> 7;
  const uint32_t s_col0 = (s_off0 ^ ((s_row0 & 7) << 4)) & 127;
  const uint32_t s_col1 = (s_off1 ^ ((s_row1 & 7) << 4)) & 127;

  const char* Ab = (const char*)A + (size_t)m0 * KB;
  const char* Bb = (const char*)Bw + (size_t)n0 * KB;

  auto STAGE = [&](int op, int h, int kt, int b) {
    const char* gb = (op ? Bb : Ab) + (size_t)(h * 128) * KB + kt * 128;
    char* lb = lds + op * 65536 + b * 32768 + h * 16384;
    gload_lds16(gb + s_row0 * KB + s_col0, lb + s_off0);
    gload_lds16(gb + s_row1 * KB + s_col1, lb + s_off1);
  };

  uint32_t axk[2];
#pragma unroll
  for (int k = 0; k < 2; ++k) axk[k] = (uint32_t)(k * 64 + r4 * 16) ^ ((r16 & 7) << 4);

  f32x4 acc[8][4] = {};
  bf16x8 bc[4][2];

  // prologue: B0,B1,A0,A1 (tile0) ; B0,B1,A0 (tile1)
  STAGE(1, 0, 0, 0); STAGE(1, 1, 0, 0); STAGE(0, 0, 0, 0); STAGE(0, 1, 0, 0);
  STAGE(1, 0, 1, 1); STAGE(1, 1, 1, 1); STAGE(0, 0, 1, 1);
  asm volatile("s_waitcnt vmcnt(6)" ::: "memory");
  barx();

  for (int kt = 0; kt < NKT; ++kt) {
    const int p = kt & 1;
    const char* abuf = lds + p * 32768;
    const char* bbuf = lds + 65536 + p * 32768;

    // ---------- phase 1: all B + A mf{0,1}; stage A1(kt+1) ----------
    {
      bf16x8 af[2][2];
#pragma unroll
      for (int nf = 0; nf < 4; ++nf)
#pragma unroll
        for (int k = 0; k < 2; ++k)
          bc[nf][k] = *(const bf16x8*)(bbuf + (nf >> 1) * 16384 +
                        (((nf & 1) * 64 + wn * 16 + r16) << 7) + axk[k]);
#pragma unroll
      for (int i = 0; i < 2; ++i)
#pragma unroll
        for (int k = 0; k < 2; ++k)
          af[i][k] = *(const bf16x8*)(abuf + ((i * 32 + wm * 16 + r16) << 7) + axk[k]);
      if (kt + 1 < NKT) STAGE(0, 1, kt + 1, (kt + 1) & 1);
      barx();
      __builtin_amdgcn_s_setprio(1);
#pragma unroll
      for (int i = 0; i < 2; ++i)
#pragma unroll
        for (int nf = 0; nf < 4; ++nf)
#pragma unroll
          for (int k = 0; k < 2; ++k)
            acc[i][nf] = __builtin_amdgcn_mfma_f32_16x16x32_bf16(bc[nf][k], af[i][k], acc[i][nf], 0, 0, 0);
      __builtin_amdgcn_s_setprio(0);
      barx();
    }
    // ---------- phase 2: A mf{2,3}; stage B0(kt+2) ----------
    {
      bf16x8 af[2][2];
#pragma unroll
      for (int i = 0; i < 2; ++i)
#pragma unroll
        for (int k = 0; k < 2; ++k)
          af[i][k] = *(const bf16x8*)(abuf + (((2 + i) * 32 + wm * 16 + r16) << 7) + axk[k]);
      if (kt + 2 < NKT) STAGE(1, 0, kt + 2, p);
      barx();
      __builtin_amdgcn_s_setprio(1);
#pragma unroll
      for (int i = 0; i < 2; ++i)
#pragma unroll
        for (int nf = 0; nf < 4; ++nf)
#pragma unroll
          for (int k = 0; k < 2; ++k)
            acc[2 + i][nf] = __builtin_amdgcn_mfma_f32_16x16x32_bf16(bc[nf][k], af[i][k], acc[2 + i][nf], 0, 0, 0);
      __builtin_amdgcn_s_setprio(0);
      barx();
    }
    // ---------- phase 3: A mf{4,5} (half1); stage B1(kt+2) ----------
    {
      bf16x8 af[2][2];
#pragma unroll
      for (int i = 0; i < 2; ++i)
#pragma unroll
        for (int k = 0; k < 2; ++k)
          af[i][k] = *(const bf16x8*)(abuf + 16384 + ((i * 32 + wm * 16 + r16) << 7) + axk[k]);
      if (kt + 2 < NKT) STAGE(1, 1, kt + 2, p);
      barx();
      __builtin_amdgcn_s_setprio(1);
#pragma unroll
      for (int i = 0; i < 2; ++i)
#pragma unroll
        for (int nf = 0; nf < 4; ++nf)
#pragma unroll
          for (int k = 0; k < 2; ++k)
            acc[4 + i][nf] = __builtin_amdgcn_mfma_f32_16x16x32_bf16(bc[nf][k], af[i][k], acc[4 + i][nf], 0, 0, 0);
      __builtin_amdgcn_s_setprio(0);
      barx();
    }
    // ---------- phase 4: A mf{6,7} (half1); stage A0(kt+2); boundary vmcnt ----------
    {
      bf16x8 af[2][2];
#pragma unroll
      for (int i = 0; i < 2; ++i)
#pragma unroll
        for (int k = 0; k < 2; ++k)
          af[i][k] = *(const bf16x8*)(abuf + 16384 + (((2 + i) * 32 + wm * 16 + r16) << 7) + axk[k]);
      if (kt + 2 < NKT) STAGE(0, 0, kt + 2, p);
      if (kt == NKT - 2) { asm volatile("s_waitcnt vmcnt(0)" ::: "memory"); }
      else if (kt < NKT - 2) { asm volatile("s_waitcnt vmcnt(6)" ::: "memory"); }
      barx();
      __builtin_amdgcn_s_setprio(1);
#pragma unroll
      for (int i = 0; i < 2; ++i)
#pragma unroll
        for (int nf = 0; nf < 4; ++nf)
#pragma unroll
          for (int k = 0; k < 2; ++k)
            acc[6 + i][nf] = __builtin_amdgcn_mfma_f32_16x16x32_bf16(bc[nf][k], af[i][k], acc[6 + i][nf], 0, 0, 0);
      __builtin_amdgcn_s_setprio(0);
      barx();
    }
  }

  // ---------- epilogue (transposed fragments) ----------
  // lane's acc[mf][nf][r]: row m = m0+mf*32+wm*16+r16 ; col n = n0+nf*64+wn*16+r4*4+r
  const int wsel = n0 >> 10;               // block-uniform (MODE 3)
  const bool do_elu = (MODE == 3) && (wsel < 2);
#pragma unroll
  for (int mf = 0; mf < 8; ++mf) {
    const int row = m0 + mf * 32 + wm * 16 + r16;
#pragma unroll
    for (int nf = 0; nf < 4; ++nf) {
      const int n = n0 + nf * 64 + wn * 16 + r4 * 4;
      if (MODE == 2) {
        f32x4 bq = *(const f32x4*)(bias + n);
        f32x4 o;
#pragma unroll
        for (int r = 0; r < 4; ++r) o[r] = acc[mf][nf][r] + bq[r];
        *(f32x4*)&((float*)Cout)[(size_t)row * DIMN + n] = o;
      } else {
        bf16x4 o;
#pragma unroll
        for (int r = 0; r < 4; ++r) {
          float v = acc[mf][nf][r];
          if (do_elu) v = (v > 0.f) ? (v + 1.f) : __expf(v);
          o[r] = (__bf16)v;
        }
        int c = n & 1023;
        int h = c >> 6, e2 = c & 63;
        int b = row >> 12, s = row & 4095;
        *(bf16x4*)&((__bf16*)Cout)[(size_t)wsel * 16777216 +
                    ((size_t)((b * HEADS + h) * SEQ + s)) * HD + e2] = o;
      }
    }
  }
}

// ---------------- kv_state via MFMA ----------------
__global__ __launch_bounds__(256) void kv_state_mfma(const __bf16* __restrict__ kp,
                                                     const __bf16* __restrict__ vb,
                                                     float* __restrict__ kv,
                                                     float* __restrict__ ks) {
  __shared__ __bf16 kt[64][136];
  __shared__ __bf16 vt[80][136];
  const int bid = blockIdx.x;      // 64 bh * 4 chunks
  const int bh = bid >> 2, nc = bid & 3;
  const int tid = threadIdx.x;
  const int lane = tid & 63;
  const int wave = tid >> 6;
  const int r16 = lane & 15, r4 = lane >> 4;

  for (int i = tid; i < 16 * 136; i += 256) {
    int rr = i / 136;
    vt[64 + rr][i - rr * 136] = (rr == 0) ? (__bf16)1.0f : (__bf16)0.0f;
  }

  const int trow = tid >> 1;
  const int tcol = (tid & 1) * 32;

  f32x4 acc[5] = {};
  bf16x8 kr[4], vr[4];

  size_t gb = ((size_t)bh * SEQ + nc * 1024 + trow) * HD + tcol;
#pragma unroll
  for (int q = 0; q < 4; ++q) {
    kr[q] = *(const bf16x8*)(kp + gb + q * 8);
    vr[q] = *(const bf16x8*)(vb + gb + q * 8);
  }

  for (int t = 0; t < 8; ++t) {
    __syncthreads();
#pragma unroll
    for (int q = 0; q < 4; ++q)
#pragma unroll
      for (int j = 0; j < 8; ++j) {
        kt[tcol + q * 8 + j][trow] = kr[q][j];
        vt[tcol + q * 8 + j][trow] = vr[q][j];
      }
    __syncthreads();
    if (t < 7) {
      size_t gb2 = ((size_t)bh * SEQ + nc * 1024 + (t + 1) * 128 + trow) * HD + tcol;
#pragma unroll
      for (int q = 0; q < 4; ++q) {
        kr[q] = *(const bf16x8*)(kp + gb2 + q * 8);
        vr[q] = *(const bf16x8*)(vb + gb2 + q * 8);
      }
    }
#pragma unroll
    for (int ksl = 0; ksl < 4; ++ksl) {
      bf16x8 af = *(const bf16x8*)&kt[wave * 16 + r16][ksl * 32 + r4 * 8];
#pragma unroll
      for (int eb = 0; eb < 5; ++eb) {
        bf16x8 bf_ = *(const bf16x8*)&vt[eb * 16 + r16][ksl * 32 + r4 * 8];
        acc[eb] = __builtin_amdgcn_mfma_f32_16x16x32_bf16(af, bf_, acc[eb], 0, 0, 0);
      }
    }
  }

#pragma unroll
  for (int eb = 0; eb < 4; ++eb)
#pragma unroll
    for (int r = 0; r < 4; ++r) {
      int d = wave * 16 + r4 * 4 + r;
      atomicAdd(&kv[(size_t)bh * 4096 + d * 64 + eb * 16 + r16], acc[eb][r]);
    }
  if (r16 == 0) {
#pragma unroll
    for (int r = 0; r < 4; ++r)
      atomicAdd(&ks[bh * 64 + wave * 16 + r4 * 4 + r], acc[4][r]);
  }
}

// ---------------- prep: kvb[bh][80][64] bf16 = {kv^T ; k_state ; 0-pad} ----------------
__global__ __launch_bounds__(256) void prep_kv_kernel(const float* __restrict__ kv,
                                                      const float* __restrict__ ks,
                                                      __bf16* __restrict__ kvb) {
  const int bh = blockIdx.x;
  const int tid = threadIdx.x;
  for (int idx = tid; idx < 80 * 64; idx += 256) {
    int e = idx >> 6, d = idx & 63;
    float v;
    if (e < 64)       v = kv[(size_t)bh * 4096 + d * 64 + e];
    else if (e == 64) v = ks[bh * 64 + d];
    else              v = 0.f;
    kvb[(size_t)bh * 5120 + idx] = (__bf16)v;
  }
}

// ---------------- attn_out (MFMA) + depthwise conv -> y (bf16) ----------------
__global__ __launch_bounds__(256) void attn_local_mfma(const __bf16* __restrict__ qp,
                                                       const __bf16* __restrict__ kvb,
                                                       const float* __restrict__ x,
                                                       const float* __restrict__ conv_w,
                                                       const float* __restrict__ conv_b,
                                                       __bf16* __restrict__ y) {
  __shared__ __bf16 qs[128 * 64];
  __shared__ __bf16 bs[80 * 64];
  const int bid = blockIdx.x;       // 64 bh * 32 chunks
  const int bh = bid >> 5;
  const int chunk = bid & 31;
  const int tid = threadIdx.x;
  const int lane = tid & 63;
  const int wave = tid >> 6;
  const int r16 = lane & 15, r4 = lane >> 4;

  const char* qbase  = (const char*)(qp + ((size_t)bh * SEQ + chunk * 128) * HD);
  const char* kvbase = (const char*)(kvb + (size_t)bh * 5120);
#pragma unroll
  for (int t = 0; t < 4; ++t) {
    int c = t * 4 + wave;
    uint32_t off = c * 1024 + lane * 16;
    gload_lds16(qbase + swz128(off), ((char*)qs) + off);
  }
#pragma unroll
  for (int t = 0; t < 3; ++t) {
    int c = t * 4 + wave;
    if (c < 10) {
      uint32_t off = c * 1024 + lane * 16;
      gload_lds16(kvbase + swz128(off), ((char*)bs) + off);
    }
  }
  __syncthreads();

  f32x4 acc[2][5] = {};
#pragma unroll
  for (int kstep = 0; kstep < 2; ++kstep) {
    bf16x8 af[2], bfr[5];
#pragma unroll
    for (int i = 0; i < 2; ++i) {
      uint32_t off = (wave * 32 + i * 16 + r16) * 128 + kstep * 64 + r4 * 16;
      af[i] = *(const bf16x8*)(((char*)qs) + swz128(off));
    }
#pragma unroll
    for (int j = 0; j < 5; ++j) {
      uint32_t off = (j * 16 + r16) * 128 + kstep * 64 + r4 * 16;
      bfr[j] = *(const bf16x8*)(((char*)bs) + swz128(off));
    }
#pragma unroll
    for (int i = 0; i < 2; ++i)
#pragma unroll
      for (int j = 0; j < 5; ++j)
        acc[i][j] = __builtin_amdgcn_mfma_f32_16x16x32_bf16(af[i], bfr[j], acc[i][j], 0, 0, 0);
  }

  const int b = bh >> 4, h = bh & 15;
  float w0[4], w1[4], w2[4], bb[4];
#pragma unroll
  for (int j = 0; j < 4; ++j) {
    int c = h * HD + j * 16 + r16;
    w0[j] = conv_w[c * 3 + 0]; w1[j] = conv_w[c * 3 + 1]; w2[j] = conv_w[c * 3 + 2];
    bb[j] = conv_b[c];
  }
#pragma unroll
  for (int i = 0; i < 2; ++i) {
#pragma unroll
    for (int r = 0; r < 4; ++r) {
      int s = chunk * 128 + wave * 32 + i * 16 + r4 * 4 + r;
      size_t m = (size_t)b * SEQ + s;
      float den = fmaxf(__shfl(acc[i][4][r], lane & 48), 1e-6f);
      float inv = 1.0f / den;
#pragma unroll
      for (int j = 0; j < 4; ++j) {
        int c = h * HD + j * 16 + r16;
        float xm = x[m * DIMN + c];
        float xl = (s > 0)       ? x[(m - 1) * DIMN + c] : 0.f;
        float xr = (s < SEQ - 1) ? x[(m + 1) * DIMN + c] : 0.f;
        float val = acc[i][j][r] * inv
                  + xl * w0[j] + xm * w1[j] + xr * w2[j] + bb[j];
        y[m * DIMN + c] = (__bf16)val;
      }
    }
  }
}

// ---------------- launch ----------------
extern "C" void kernel_launch(void* const* d_in, const int* in_sizes, int n_in,
                              void* d_out, int out_size, void* d_ws, size_t ws_size,
                              hipStream_t stream) {
  const float* x  = (const float*)d_in[0];
  const float* Wq = (const float*)d_in[1];
  const float* Wk = (const float*)d_in[2];
  const float* Wv = (const float*)d_in[3];
  const float* Wp = (const float*)d_in[4];
  const float* bp = (const float*)d_in[5];
  const float* cw = (const float*)d_in[6];
  const float* cb = (const float*)d_in[7];
  float* out = (float*)d_out;

  char* ws = (char*)d_ws;
  const size_t MB = 1024 * 1024;
  __bf16* xb  = (__bf16*)(ws);             // 32 MB; later aliased as y
  __bf16* y   = xb;
  __bf16* qp  = (__bf16*)(ws + 32 * MB);   // q,k,v contiguous: qp + wsel*16777216
  __bf16* kp  = (__bf16*)(ws + 64 * MB);
  __bf16* vb  = (__bf16*)(ws + 96 * MB);
  __bf16* wqb = (__bf16*)(ws + 128 * MB);  // wq,wk,wv contiguous = fused [3072][1024]
  __bf16* wkb = (__bf16*)(ws + 130 * MB);
  __bf16* wvb = (__bf16*)(ws + 132 * MB);
  __bf16* wpb = (__bf16*)(ws + 134 * MB);
  float*  kv  = (float*)(ws + 136 * MB);
  float*  ks  = (float*)(ws + 137 * MB);
  __bf16* kvb = wqb;                       // wqb dead after QKV gemm

  // fused casts: 4194304 (x) + 4*262144 (weights) = 5242880 quads -> 20480 blocks
  cast_all_kernel<<<20480, 256, 0, stream>>>(x, Wq, Wk, Wv, Wp, xb, wqb, wkb, wvb, wpb);

  // fused QKV: M=16384, N=3072 -> 64 x 12 = 768 blocks
  gemm256<3, 12><<<768, 512, 0, stream>>>(xb, wqb, qp, nullptr);

  hipMemsetAsync(kv, 0, 64 * 4096 * 4 + 64 * 64 * 4, stream);
  kv_state_mfma<<<256, 256, 0, stream>>>(kp, vb, kv, ks);
  prep_kv_kernel<<<64, 256, 0, stream>>>(kv, ks, kvb);

  attn_local_mfma<<<2048, 256, 0, stream>>>(qp, kvb, x, cw, cb, y);

  // final: M=16384, N=1024 -> 64 x 4 = 256 blocks
  gemm256<2, 4><<<256, 512, 0, stream>>>(y, wpb, out, bp);
}

// Round 6
// 237.141 us; speedup vs baseline: 1.0183x; 1.0183x over previous
//
#include <hip/hip_runtime.h>
#include <hip/hip_bf16.h>
#include <stdint.h>

#define DIMN 1024
#define HEADS 16
#define HD 64
#define BATCH 4
#define SEQ 4096
#define M_TOT (BATCH*SEQ)   // 16384

typedef __attribute__((ext_vector_type(8))) __bf16 bf16x8;
typedef __attribute__((ext_vector_type(4))) __bf16 bf16x4;
typedef __attribute__((ext_vector_type(4))) float f32x4;

__device__ __forceinline__ void gload_lds16(const void* g, void* l) {
  __builtin_amdgcn_global_load_lds(
      (const __attribute__((address_space(1))) void*)(uintptr_t)g,
      (__attribute__((address_space(3))) void*)(uint32_t)(uintptr_t)l,
      16, 0, 0);
}

__device__ __forceinline__ uint32_t swz128(uint32_t off) {
  return off ^ (((off >> 7) & 7) << 4);
}

__device__ __forceinline__ void lfence() { asm volatile("" ::: "memory"); }
__device__ __forceinline__ void barx() { lfence(); __builtin_amdgcn_s_barrier(); lfence(); }

// ---------------- fused cast: x (4194304 quads) then Wq/Wk/Wv/Wp (262144 each) ----------------
__global__ __launch_bounds__(256) void cast_all_kernel(const float* __restrict__ x,
                                                       const float* __restrict__ wq,
                                                       const float* __restrict__ wk,
                                                       const float* __restrict__ wv,
                                                       const float* __restrict__ wp,
                                                       __bf16* __restrict__ xb,
                                                       __bf16* __restrict__ wqb,
                                                       __bf16* __restrict__ wkb,
                                                       __bf16* __restrict__ wvb,
                                                       __bf16* __restrict__ wpb) {
  int i = blockIdx.x * 256 + threadIdx.x;
  const float* src; __bf16* dst; int j;
  if (i < 4194304)      { src = x;  dst = xb;  j = i; }
  else {
    int t = i - 4194304;
    int w = t >> 18; j = t & 262143;
    if      (w == 0) { src = wq; dst = wqb; }
    else if (w == 1) { src = wk; dst = wkb; }
    else if (w == 2) { src = wv; dst = wvb; }
    else             { src = wp; dst = wpb; }
  }
  f32x4 v = ((const f32x4*)src)[j];
  bf16x4 o;
  o[0] = (__bf16)v[0]; o[1] = (__bf16)v[1]; o[2] = (__bf16)v[2]; o[3] = (__bf16)v[3];
  ((bf16x4*)dst)[j] = o;
}

// ---------------- 256x256 GEMM, 4 phases/K-tile, ONE barrier per phase ----------------
// Region between barriers = [MFMA_p ; reads_{p+1} ; stage_{p+1}] -> LDS reads
// overlap MFMA (ILP within wave + TLP via <=1-phase wave skew).
// Operand-swapped MFMA (mfma(B,A)) -> lane holds 4 consecutive output cols of one row.
// MODE 2: v + bias -> f32 row-major [M,1024]
// MODE 3: fused QKV: n<1024 -> q (elu+1), <2048 -> k (elu+1), else v; bf16 head layout
template <int MODE, int NT>
__global__ __launch_bounds__(512, 2) void gemm256(const __bf16* __restrict__ A,
                                                  const __bf16* __restrict__ Bw,
                                                  void* __restrict__ Cout,
                                                  const float* __restrict__ bias) {
  __shared__ char lds[131072];   // A: [0,65536) bufs 0/1; B: [65536,131072)
  const int KB = DIMN * 2;       // 2048 B row stride
  const int NKT = DIMN / 64;     // 16 K-tiles
  const int bid = blockIdx.x;
  const int x = bid & 7, jj = bid >> 3;
  const int n_t = jj % NT, m_t = (jj / NT) * 8 + x;
  const int m0 = m_t * 256, n0 = n_t * 256;
  const int tid = threadIdx.x;
  const int lane = tid & 63;
  const int wave = tid >> 6;
  const int wm = wave >> 2;        // 0..1
  const int wn = wave & 3;         // 0..3
  const int r16 = lane & 15, r4 = lane >> 4;

  const uint32_t s_off0 = tid * 16;
  const uint32_t s_off1 = 8192 + tid * 16;
  const uint32_t s_row0 = s_off0 >> 7, s_row1 = s_off1 >> 7;
  const uint32_t s_col0 = (s_off0 ^ ((s_row0 & 7) << 4)) & 127;
  const uint32_t s_col1 = (s_off1 ^ ((s_row1 & 7) << 4)) & 127;

  const char* Ab = (const char*)A + (size_t)m0 * KB;
  const char* Bb = (const char*)Bw + (size_t)n0 * KB;

  auto STAGE = [&](int op, int h, int kt, int b) {
    const char* gb = (op ? Bb : Ab) + (size_t)(h * 128) * KB + kt * 128;
    char* lb = lds + op * 65536 + b * 32768 + h * 16384;
    gload_lds16(gb + s_row0 * KB + s_col0, lb + s_off0);
    gload_lds16(gb + s_row1 * KB + s_col1, lb + s_off1);
  };

  uint32_t axk[2];
#pragma unroll
  for (int k = 0; k < 2; ++k) axk[k] = (uint32_t)(k * 64 + r4 * 16) ^ ((r16 & 7) << 4);

  f32x4 acc[8][4] = {};
  bf16x8 bc[4][2];

  // prologue: B0,B1,A0,A1 (tile0) ; B0,B1,A0 (tile1)
  STAGE(1, 0, 0, 0); STAGE(1, 1, 0, 0); STAGE(0, 0, 0, 0); STAGE(0, 1, 0, 0);
  STAGE(1, 0, 1, 1); STAGE(1, 1, 1, 1); STAGE(0, 0, 1, 1);
  asm volatile("s_waitcnt vmcnt(6)" ::: "memory");
  barx();

  for (int kt = 0; kt < NKT; ++kt) {
    const int p = kt & 1;
    const char* abuf = lds + p * 32768;
    const char* bbuf = lds + 65536 + p * 32768;

    // ---------- phase 1: all B + A mf{0,1}; stage A1(kt+1) ----------
    {
      bf16x8 af[2][2];
#pragma unroll
      for (int nf = 0; nf < 4; ++nf)
#pragma unroll
        for (int k = 0; k < 2; ++k)
          bc[nf][k] = *(const bf16x8*)(bbuf + (nf >> 1) * 16384 +
                        (((nf & 1) * 64 + wn * 16 + r16) << 7) + axk[k]);
#pragma unroll
      for (int i = 0; i < 2; ++i)
#pragma unroll
        for (int k = 0; k < 2; ++k)
          af[i][k] = *(const bf16x8*)(abuf + ((i * 32 + wm * 16 + r16) << 7) + axk[k]);
      if (kt + 1 < NKT) STAGE(0, 1, kt + 1, (kt + 1) & 1);
      barx();
      __builtin_amdgcn_s_setprio(1);
#pragma unroll
      for (int i = 0; i < 2; ++i)
#pragma unroll
        for (int nf = 0; nf < 4; ++nf)
#pragma unroll
          for (int k = 0; k < 2; ++k)
            acc[i][nf] = __builtin_amdgcn_mfma_f32_16x16x32_bf16(bc[nf][k], af[i][k], acc[i][nf], 0, 0, 0);
      __builtin_amdgcn_s_setprio(0);
    }
    // ---------- phase 2: A mf{2,3}; stage B0(kt+2) ----------
    {
      bf16x8 af[2][2];
#pragma unroll
      for (int i = 0; i < 2; ++i)
#pragma unroll
        for (int k = 0; k < 2; ++k)
          af[i][k] = *(const bf16x8*)(abuf + (((2 + i) * 32 + wm * 16 + r16) << 7) + axk[k]);
      if (kt + 2 < NKT) STAGE(1, 0, kt + 2, p);
      barx();
      __builtin_amdgcn_s_setprio(1);
#pragma unroll
      for (int i = 0; i < 2; ++i)
#pragma unroll
        for (int nf = 0; nf < 4; ++nf)
#pragma unroll
          for (int k = 0; k < 2; ++k)
            acc[2 + i][nf] = __builtin_amdgcn_mfma_f32_16x16x32_bf16(bc[nf][k], af[i][k], acc[2 + i][nf], 0, 0, 0);
      __builtin_amdgcn_s_setprio(0);
    }
    // ---------- phase 3: A mf{4,5} (half1); stage B1(kt+2) ----------
    {
      bf16x8 af[2][2];
#pragma unroll
      for (int i = 0; i < 2; ++i)
#pragma unroll
        for (int k = 0; k < 2; ++k)
          af[i][k] = *(const bf16x8*)(abuf + 16384 + ((i * 32 + wm * 16 + r16) << 7) + axk[k]);
      if (kt + 2 < NKT) STAGE(1, 1, kt + 2, p);
      barx();
      __builtin_amdgcn_s_setprio(1);
#pragma unroll
      for (int i = 0; i < 2; ++i)
#pragma unroll
        for (int nf = 0; nf < 4; ++nf)
#pragma unroll
          for (int k = 0; k < 2; ++k)
            acc[4 + i][nf] = __builtin_amdgcn_mfma_f32_16x16x32_bf16(bc[nf][k], af[i][k], acc[4 + i][nf], 0, 0, 0);
      __builtin_amdgcn_s_setprio(0);
    }
    // ---------- phase 4: A mf{6,7} (half1); stage A0(kt+2); boundary vmcnt ----------
    {
      bf16x8 af[2][2];
#pragma unroll
      for (int i = 0; i < 2; ++i)
#pragma unroll
        for (int k = 0; k < 2; ++k)
          af[i][k] = *(const bf16x8*)(abuf + 16384 + (((2 + i) * 32 + wm * 16 + r16) << 7) + axk[k]);
      if (kt + 2 < NKT) STAGE(0, 0, kt + 2, p);
      if (kt == NKT - 2) { asm volatile("s_waitcnt vmcnt(0)" ::: "memory"); }
      else if (kt < NKT - 2) { asm volatile("s_waitcnt vmcnt(6)" ::: "memory"); }
      barx();
      __builtin_amdgcn_s_setprio(1);
#pragma unroll
      for (int i = 0; i < 2; ++i)
#pragma unroll
        for (int nf = 0; nf < 4; ++nf)
#pragma unroll
          for (int k = 0; k < 2; ++k)
            acc[6 + i][nf] = __builtin_amdgcn_mfma_f32_16x16x32_bf16(bc[nf][k], af[i][k], acc[6 + i][nf], 0, 0, 0);
      __builtin_amdgcn_s_setprio(0);
    }
  }

  // ---------- epilogue (transposed fragments) ----------
  // lane's acc[mf][nf][r]: row m = m0+mf*32+wm*16+r16 ; col n = n0+nf*64+wn*16+r4*4+r
  const int wsel = n0 >> 10;               // block-uniform (MODE 3)
  const bool do_elu = (MODE == 3) && (wsel < 2);
#pragma unroll
  for (int mf = 0; mf < 8; ++mf) {
    const int row = m0 + mf * 32 + wm * 16 + r16;
#pragma unroll
    for (int nf = 0; nf < 4; ++nf) {
      const int n = n0 + nf * 64 + wn * 16 + r4 * 4;
      if (MODE == 2) {
        f32x4 bq = *(const f32x4*)(bias + n);
        f32x4 o;
#pragma unroll
        for (int r = 0; r < 4; ++r) o[r] = acc[mf][nf][r] + bq[r];
        *(f32x4*)&((float*)Cout)[(size_t)row * DIMN + n] = o;
      } else {
        bf16x4 o;
#pragma unroll
        for (int r = 0; r < 4; ++r) {
          float v = acc[mf][nf][r];
          if (do_elu) v = (v > 0.f) ? (v + 1.f) : __expf(v);
          o[r] = (__bf16)v;
        }
        int c = n & 1023;
        int h = c >> 6, e2 = c & 63;
        int b = row >> 12, s = row & 4095;
        *(bf16x4*)&((__bf16*)Cout)[(size_t)wsel * 16777216 +
                    ((size_t)((b * HEADS + h) * SEQ + s)) * HD + e2] = o;
      }
    }
  }
}

// ---------------- kv_state via MFMA ----------------
__global__ __launch_bounds__(256) void kv_state_mfma(const __bf16* __restrict__ kp,
                                                     const __bf16* __restrict__ vb,
                                                     float* __restrict__ kv,
                                                     float* __restrict__ ks) {
  __shared__ __bf16 kt[64][136];
  __shared__ __bf16 vt[80][136];
  const int bid = blockIdx.x;      // 64 bh * 4 chunks
  const int bh = bid >> 2, nc = bid & 3;
  const int tid = threadIdx.x;
  const int lane = tid & 63;
  const int wave = tid >> 6;
  const int r16 = lane & 15, r4 = lane >> 4;

  for (int i = tid; i < 16 * 136; i += 256) {
    int rr = i / 136;
    vt[64 + rr][i - rr * 136] = (rr == 0) ? (__bf16)1.0f : (__bf16)0.0f;
  }

  const int trow = tid >> 1;
  const int tcol = (tid & 1) * 32;

  f32x4 acc[5] = {};
  bf16x8 kr[4], vr[4];

  size_t gb = ((size_t)bh * SEQ + nc * 1024 + trow) * HD + tcol;
#pragma unroll
  for (int q = 0; q < 4; ++q) {
    kr[q] = *(const bf16x8*)(kp + gb + q * 8);
    vr[q] = *(const bf16x8*)(vb + gb + q * 8);
  }

  for (int t = 0; t < 8; ++t) {
    __syncthreads();
#pragma unroll
    for (int q = 0; q < 4; ++q)
#pragma unroll
      for (int j = 0; j < 8; ++j) {
        kt[tcol + q * 8 + j][trow] = kr[q][j];
        vt[tcol + q * 8 + j][trow] = vr[q][j];
      }
    __syncthreads();
    if (t < 7) {
      size_t gb2 = ((size_t)bh * SEQ + nc * 1024 + (t + 1) * 128 + trow) * HD + tcol;
#pragma unroll
      for (int q = 0; q < 4; ++q) {
        kr[q] = *(const bf16x8*)(kp + gb2 + q * 8);
        vr[q] = *(const bf16x8*)(vb + gb2 + q * 8);
      }
    }
#pragma unroll
    for (int ksl = 0; ksl < 4; ++ksl) {
      bf16x8 af = *(const bf16x8*)&kt[wave * 16 + r16][ksl * 32 + r4 * 8];
#pragma unroll
      for (int eb = 0; eb < 5; ++eb) {
        bf16x8 bf_ = *(const bf16x8*)&vt[eb * 16 + r16][ksl * 32 + r4 * 8];
        acc[eb] = __builtin_amdgcn_mfma_f32_16x16x32_bf16(af, bf_, acc[eb], 0, 0, 0);
      }
    }
  }

#pragma unroll
  for (int eb = 0; eb < 4; ++eb)
#pragma unroll
    for (int r = 0; r < 4; ++r) {
      int d = wave * 16 + r4 * 4 + r;
      atomicAdd(&kv[(size_t)bh * 4096 + d * 64 + eb * 16 + r16], acc[eb][r]);
    }
  if (r16 == 0) {
#pragma unroll
    for (int r = 0; r < 4; ++r)
      atomicAdd(&ks[bh * 64 + wave * 16 + r4 * 4 + r], acc[4][r]);
  }
}

// ---------------- prep: kvb[bh][80][64] bf16 = {kv^T ; k_state ; 0-pad} ----------------
__global__ __launch_bounds__(256) void prep_kv_kernel(const float* __restrict__ kv,
                                                      const float* __restrict__ ks,
                                                      __bf16* __restrict__ kvb) {
  const int bh = blockIdx.x;
  const int tid = threadIdx.x;
  for (int idx = tid; idx < 80 * 64; idx += 256) {
    int e = idx >> 6, d = idx & 63;
    float v;
    if (e < 64)       v = kv[(size_t)bh * 4096 + d * 64 + e];
    else if (e == 64) v = ks[bh * 64 + d];
    else              v = 0.f;
    kvb[(size_t)bh * 5120 + idx] = (__bf16)v;
  }
}

// ---------------- attn_out (MFMA) + depthwise conv -> y (bf16) ----------------
__global__ __launch_bounds__(256) void attn_local_mfma(const __bf16* __restrict__ qp,
                                                       const __bf16* __restrict__ kvb,
                                                       const float* __restrict__ x,
                                                       const float* __restrict__ conv_w,
                                                       const float* __restrict__ conv_b,
                                                       __bf16* __restrict__ y) {
  __shared__ __bf16 qs[128 * 64];
  __shared__ __bf16 bs[80 * 64];
  const int bid = blockIdx.x;       // 64 bh * 32 chunks
  const int bh = bid >> 5;
  const int chunk = bid & 31;
  const int tid = threadIdx.x;
  const int lane = tid & 63;
  const int wave = tid >> 6;
  const int r16 = lane & 15, r4 = lane >> 4;

  const char* qbase  = (const char*)(qp + ((size_t)bh * SEQ + chunk * 128) * HD);
  const char* kvbase = (const char*)(kvb + (size_t)bh * 5120);
#pragma unroll
  for (int t = 0; t < 4; ++t) {
    int c = t * 4 + wave;
    uint32_t off = c * 1024 + lane * 16;
    gload_lds16(qbase + swz128(off), ((char*)qs) + off);
  }
#pragma unroll
  for (int t = 0; t < 3; ++t) {
    int c = t * 4 + wave;
    if (c < 10) {
      uint32_t off = c * 1024 + lane * 16;
      gload_lds16(kvbase + swz128(off), ((char*)bs) + off);
    }
  }
  __syncthreads();

  f32x4 acc[2][5] = {};
#pragma unroll
  for (int kstep = 0; kstep < 2; ++kstep) {
    bf16x8 af[2], bfr[5];
#pragma unroll
    for (int i = 0; i < 2; ++i) {
      uint32_t off = (wave * 32 + i * 16 + r16) * 128 + kstep * 64 + r4 * 16;
      af[i] = *(const bf16x8*)(((char*)qs) + swz128(off));
    }
#pragma unroll
    for (int j = 0; j < 5; ++j) {
      uint32_t off = (j * 16 + r16) * 128 + kstep * 64 + r4 * 16;
      bfr[j] = *(const bf16x8*)(((char*)bs) + swz128(off));
    }
#pragma unroll
    for (int i = 0; i < 2; ++i)
#pragma unroll
      for (int j = 0; j < 5; ++j)
        acc[i][j] = __builtin_amdgcn_mfma_f32_16x16x32_bf16(af[i], bfr[j], acc[i][j], 0, 0, 0);
  }

  const int b = bh >> 4, h = bh & 15;
  float w0[4], w1[4], w2[4], bb[4];
#pragma unroll
  for (int j = 0; j < 4; ++j) {
    int c = h * HD + j * 16 + r16;
    w0[j] = conv_w[c * 3 + 0]; w1[j] = conv_w[c * 3 + 1]; w2[j] = conv_w[c * 3 + 2];
    bb[j] = conv_b[c];
  }
#pragma unroll
  for (int i = 0; i < 2; ++i) {
#pragma unroll
    for (int r = 0; r < 4; ++r) {
      int s = chunk * 128 + wave * 32 + i * 16 + r4 * 4 + r;
      size_t m = (size_t)b * SEQ + s;
      float den = fmaxf(__shfl(acc[i][4][r], lane & 48), 1e-6f);
      float inv = 1.0f / den;
#pragma unroll
      for (int j = 0; j < 4; ++j) {
        int c = h * HD + j * 16 + r16;
        float xm = x[m * DIMN + c];
        float xl = (s > 0)       ? x[(m - 1) * DIMN + c] : 0.f;
        float xr = (s < SEQ - 1) ? x[(m + 1) * DIMN + c] : 0.f;
        float val = acc[i][j][r] * inv
                  + xl * w0[j] + xm * w1[j] + xr * w2[j] + bb[j];
        y[m * DIMN + c] = (__bf16)val;
      }
    }
  }
}

// ---------------- launch ----------------
extern "C" void kernel_launch(void* const* d_in, const int* in_sizes, int n_in,
                              void* d_out, int out_size, void* d_ws, size_t ws_size,
                              hipStream_t stream) {
  const float* x  = (const float*)d_in[0];
  const float* Wq = (const float*)d_in[1];
  const float* Wk = (const float*)d_in[2];
  const float* Wv = (const float*)d_in[3];
  const float* Wp = (const float*)d_in[4];
  const float* bp = (const float*)d_in[5];
  const float* cw = (const float*)d_in[6];
  const float* cb = (const float*)d_in[7];
  float* out = (float*)d_out;

  char* ws = (char*)d_ws;
  const size_t MB = 1024 * 1024;
  __bf16* xb  = (__bf16*)(ws);             // 32 MB; later aliased as y
  __bf16* y   = xb;
  __bf16* qp  = (__bf16*)(ws + 32 * MB);   // q,k,v contiguous: qp + wsel*16777216
  __bf16* kp  = (__bf16*)(ws + 64 * MB);
  __bf16* vb  = (__bf16*)(ws + 96 * MB);
  __bf16* wqb = (__bf16*)(ws + 128 * MB);  // wq,wk,wv contiguous = fused [3072][1024]
  __bf16* wkb = (__bf16*)(ws + 130 * MB);
  __bf16* wvb = (__bf16*)(ws + 132 * MB);
  __bf16* wpb = (__bf16*)(ws + 134 * MB);
  float*  kv  = (float*)(ws + 136 * MB);
  float*  ks  = (float*)(ws + 137 * MB);
  __bf16* kvb = wqb;                       // wqb dead after QKV gemm

  // fused casts: 4194304 (x) + 4*262144 (weights) = 5242880 quads -> 20480 blocks
  cast_all_kernel<<<20480, 256, 0, stream>>>(x, Wq, Wk, Wv, Wp, xb, wqb, wkb, wvb, wpb);

  // fused QKV: M=16384, N=3072 -> 64 x 12 = 768 blocks
  gemm256<3, 12><<<768, 512, 0, stream>>>(xb, wqb, qp, nullptr);

  hipMemsetAsync(kv, 0, 64 * 4096 * 4 + 64 * 64 * 4, stream);
  kv_state_mfma<<<256, 256, 0, stream>>>(kp, vb, kv, ks);
  prep_kv_kernel<<<64, 256, 0, stream>>>(kv, ks, kvb);

  attn_local_mfma<<<2048, 256, 0, stream>>>(qp, kvb, x, cw, cb, y);

  // final: M=16384, N=1024 -> 64 x 4 = 256 blocks
  gemm256<2, 4><<<256, 512, 0, stream>>>(y, wpb, out, bp);
}